// Round 6
// baseline (364.935 us; speedup 1.0000x reference)
//
#include <hip/hip_runtime.h>
#include <hip/hip_bf16.h>
#include <stdint.h>

typedef __bf16 bf16_t;
typedef __bf16 bf16x2 __attribute__((ext_vector_type(2)));
typedef __bf16 bf16x4 __attribute__((ext_vector_type(4)));
typedef __bf16 bf16x8 __attribute__((ext_vector_type(8)));
typedef float f32x4 __attribute__((ext_vector_type(4)));

// Async global->LDS, 16B per lane. LDS dst is wave-uniform base + lane*16.
template <typename T>
__device__ __forceinline__ void async_ld16(const T* g, T* lds) {
    __builtin_amdgcn_global_load_lds(
        (__attribute__((address_space(1))) void*)g,
        (__attribute__((address_space(3))) void*)lds,
        16, 0, 0);
}

// ---------------- prep: weight transposes only (X handled in GEMM1) ----------

__device__ __forceinline__ void transpose_tile(
    const float* __restrict__ in, bf16_t* __restrict__ out,
    int R, int C, int Cp, int tileIdx, int tid, float (*tile)[33])
{
    const int tilesX = Cp / 32;
    const int c0 = (tileIdx % tilesX) * 32;
    const int r0 = (tileIdx / tilesX) * 32;
    const int tx = tid & 31;
    const int ty = tid >> 5;   // 0..7
#pragma unroll
    for (int i = 0; i < 32; i += 8) {
        int rr = r0 + ty + i, cc = c0 + tx;
        float v = 0.f;
        if (cc < C) v = in[(size_t)rr * C + cc];   // R tiles always in-bounds
        tile[ty + i][tx] = v;
    }
    __syncthreads();
    // vectorized write-back: each thread stores bf16x2 (two consecutive R cols)
    const int px = tid & 15;          // pair index along R
    const int py = tid >> 4;          // 0..15 -> output row within tile
#pragma unroll
    for (int i = 0; i < 32; i += 16) {
        int oc = c0 + py + i;         // output row (original column, zero-padded)
        int orr = r0 + px * 2;        // output col (original row), pair base
        bf16x2 o = { (bf16_t)tile[px * 2][py + i], (bf16_t)tile[px * 2 + 1][py + i] };
        *(bf16x2*)&out[(size_t)oc * R + orr] = o;
    }
}

__global__ void prep_weights(const float* __restrict__ W1, bf16_t* __restrict__ W1T,
                             const float* __restrict__ W2, bf16_t* __restrict__ W2T,
                             const float* __restrict__ Wc, bf16_t* __restrict__ WcT,
                             int FEAT, int HID, int NC, int NCP, int t1, int t2)
{
    __shared__ float tile[32][33];
    int bid = blockIdx.x;
    int tid = threadIdx.x;
    if (bid < t1) { transpose_tile(W1, W1T, FEAT, HID, HID, bid, tid, tile); return; }
    bid -= t1;
    if (bid < t2) { transpose_tile(W2, W2T, HID, HID, HID, bid, tid, tile); return; }
    bid -= t2;
    transpose_tile(Wc, WcT, HID, NC, NCP, bid, tid, tile);
}

// ------ GEMM1: A fp32 (X, converted at fragment read), B bf16, split-K -------
// A: [M][K] fp32. B: [N][K] bf16 (W1T). P: [S][M][N] fp32 partials.
// R4-proven global_load_lds single-buffer structure (pipelining attempts all
// regress — m97 plateau is structural). A staged as fp32 (128x32 = 16 KB),
// B as bf16 (8 KB). Swizzles: A rows are 128 B (8 chunks) -> phys = c ^ (row&7);
// B rows are 64 B (4 chunks) -> phys = c ^ ((row>>1)&3)  [R4, measured 0 conflicts].
__global__ __launch_bounds__(256) void gemm128_xf32(
    const float* __restrict__ A, const bf16_t* __restrict__ B,
    float* __restrict__ P, int M, int N, int K, int KC)
{
    __shared__ __align__(16) float  Asm[128 * 32];
    __shared__ __align__(16) bf16_t Bsm[128 * 32];

    const int tid  = threadIdx.x;
    const int wave = tid >> 6;
    const int lane = tid & 63;
    const int bm = blockIdx.x, bn = blockIdx.y, s = blockIdx.z;

    const float*  Ab = A + (size_t)bm * 128 * K + (size_t)s * KC;
    const bf16_t* Bb = B + (size_t)bn * 128 * K + (size_t)s * KC;

    // A staging: per issue 64 lanes x 16B = 8 fp32 rows. row-in-group = lane>>3,
    // landing chunk = lane&7; fetch logical chunk (lane&7)^(row&7).
    const int arow = lane >> 3;
    const int akf  = ((lane & 7) ^ arow) * 4;          // fp32 element offset
    // B staging (R4): per issue 16 rows. row-in-group = lane>>2, chunk = lane&3;
    // fetch logical chunk (lane&3)^((row>>1)&3).
    const int brow = lane >> 2;
    const int bke  = ((lane & 3) ^ ((brow >> 1) & 3)) * 8;  // bf16 element offset

    // wave quadrant (64x64) within 128x128 tile
    const int wm = (wave >> 1) * 64;
    const int wn = (wave & 1) * 64;
    const int r  = lane & 15;
    const int q  = lane >> 4;
    const int physB = (q ^ ((r >> 1) & 3)) * 8;        // B frag: bf16 elem offset
    const int pA0 = ((2 * q) ^ (r & 7)) * 4;           // A frag lo: fp32 elem offset
    const int pA1 = ((2 * q + 1) ^ (r & 7)) * 4;       // A frag hi

    f32x4 acc[4][4];
#pragma unroll
    for (int i = 0; i < 4; ++i)
#pragma unroll
        for (int j = 0; j < 4; ++j)
            acc[i][j] = f32x4{0.f, 0.f, 0.f, 0.f};

    for (int k0 = 0; k0 < KC; k0 += 32) {
        __syncthreads();
        // A: 16 issues of 8 rows (4 per wave); B: 8 issues of 16 rows (2 per wave)
#pragma unroll
        for (int i = 0; i < 4; ++i) {
            const int rb = wave * 32 + i * 8;
            async_ld16(Ab + (size_t)(rb + arow) * K + (k0 + akf), &Asm[rb * 32]);
        }
#pragma unroll
        for (int i = 0; i < 2; ++i) {
            const int rb = (wave * 2 + i) * 16;
            async_ld16(Bb + (size_t)(rb + brow) * K + (k0 + bke), &Bsm[rb * 32]);
        }
        __syncthreads();

        bf16x8 af[4], bfr[4];
#pragma unroll
        for (int i = 0; i < 4; ++i) {
            const int rr = (wm + i * 16 + r) * 32;
            f32x4 lo = *(const f32x4*)&Asm[rr + pA0];
            f32x4 hi = *(const f32x4*)&Asm[rr + pA1];
            af[i][0] = (bf16_t)lo[0]; af[i][1] = (bf16_t)lo[1];
            af[i][2] = (bf16_t)lo[2]; af[i][3] = (bf16_t)lo[3];
            af[i][4] = (bf16_t)hi[0]; af[i][5] = (bf16_t)hi[1];
            af[i][6] = (bf16_t)hi[2]; af[i][7] = (bf16_t)hi[3];
        }
#pragma unroll
        for (int j = 0; j < 4; ++j)
            bfr[j] = *(const bf16x8*)&Bsm[(wn + j * 16 + r) * 32 + physB];
#pragma unroll
        for (int i = 0; i < 4; ++i)
#pragma unroll
            for (int j = 0; j < 4; ++j)
                acc[i][j] = __builtin_amdgcn_mfma_f32_16x16x32_bf16(af[i], bfr[j], acc[i][j], 0, 0, 0);
    }

    // epilogue: C/D layout col=lane&15, row=(lane>>4)*4+reg
    float* Pb = P + ((size_t)s * M + (size_t)bm * 128) * N + (size_t)bn * 128;
    const int r4 = q * 4;
    const int c  = r;
#pragma unroll
    for (int i = 0; i < 4; ++i)
#pragma unroll
        for (int j = 0; j < 4; ++j)
#pragma unroll
            for (int rg = 0; rg < 4; ++rg)
                Pb[(size_t)(wm + i * 16 + r4 + rg) * N + (wn + j * 16 + c)] = acc[i][j][rg];
}

// ---------------- GEMM 64x64, BK=64, full-K, fused bias(+ReLU) epilogue ------
template <bool RELU, typename OutT>
__global__ __launch_bounds__(256) void gemm64_fused(
    const bf16_t* __restrict__ A, const bf16_t* __restrict__ B,
    const float* __restrict__ bias, OutT* __restrict__ out,
    int K, int Nout)
{
    __shared__ __align__(16) bf16_t Asm[64 * 64];
    __shared__ __align__(16) bf16_t Bsm[64 * 64];

    const int tid  = threadIdx.x;
    const int wave = tid >> 6;
    const int lane = tid & 63;
    const int bm = blockIdx.x, bn = blockIdx.y;

    const bf16_t* Ab = A + (size_t)bm * 64 * K;
    const bf16_t* Bb = B + (size_t)bn * 64 * K;

    const int sr = lane >> 3;
    const int sk = ((lane & 7) ^ (sr & 7)) * 8;

    const int wm = (wave >> 1) * 32;
    const int wn = (wave & 1) * 32;
    const int r  = lane & 15;
    const int q  = lane >> 4;

    f32x4 acc[2][2];
#pragma unroll
    for (int i = 0; i < 2; ++i)
#pragma unroll
        for (int j = 0; j < 2; ++j)
            acc[i][j] = f32x4{0.f, 0.f, 0.f, 0.f};

    for (int k0 = 0; k0 < K; k0 += 64) {
        __syncthreads();
#pragma unroll
        for (int i = 0; i < 2; ++i) {
            const int rb = wave * 16 + i * 8;
            async_ld16(Ab + (size_t)(rb + sr) * K + (k0 + sk), &Asm[rb * 64]);
            async_ld16(Bb + (size_t)(rb + sr) * K + (k0 + sk), &Bsm[rb * 64]);
        }
        __syncthreads();

#pragma unroll
        for (int rnd = 0; rnd < 2; ++rnd) {
            bf16x8 af[2], bfr[2];
#pragma unroll
            for (int i = 0; i < 2; ++i)
                af[i] = *(const bf16x8*)&Asm[(wm + i * 16 + r) * 64
                                             + ((rnd * 4 + q) ^ (r & 7)) * 8];
#pragma unroll
            for (int j = 0; j < 2; ++j)
                bfr[j] = *(const bf16x8*)&Bsm[(wn + j * 16 + r) * 64
                                              + ((rnd * 4 + q) ^ (r & 7)) * 8];
#pragma unroll
            for (int i = 0; i < 2; ++i)
#pragma unroll
                for (int j = 0; j < 2; ++j)
                    acc[i][j] = __builtin_amdgcn_mfma_f32_16x16x32_bf16(af[i], bfr[j], acc[i][j], 0, 0, 0);
        }
    }

    const int r4 = (lane >> 4) * 4;
    const int c  = lane & 15;
#pragma unroll
    for (int i = 0; i < 2; ++i)
#pragma unroll
        for (int j = 0; j < 2; ++j) {
            const int col = bn * 64 + wn + j * 16 + c;
            if (col < Nout) {
                const float bv = bias[col];
#pragma unroll
                for (int rg = 0; rg < 4; ++rg) {
                    const int row = bm * 64 + wm + i * 16 + r4 + rg;
                    float v = acc[i][j][rg] + bv;
                    if (RELU) v = fmaxf(v, 0.f);
                    out[(size_t)row * Nout + col] = (OutT)v;
                }
            }
        }
}

// ---------------- split-K reduction for layer 1 ----------------

template <int S>
__global__ void reduce_relu_bf16_k(const float* __restrict__ P, const float* __restrict__ bias,
                                   bf16_t* __restrict__ h, int MN, int Nm1) {
    int i4 = (blockIdx.x * 256 + threadIdx.x) * 4;
    if (i4 >= MN) return;
    int n = i4 & Nm1;
    float4 a = *(const float4*)(bias + n);
#pragma unroll
    for (int s = 0; s < S; ++s) {
        float4 p = *(const float4*)(P + (size_t)s * MN + i4);
        a.x += p.x; a.y += p.y; a.z += p.z; a.w += p.w;
    }
    a.x = fmaxf(a.x, 0.f); a.y = fmaxf(a.y, 0.f);
    a.z = fmaxf(a.z, 0.f); a.w = fmaxf(a.w, 0.f);
    bf16x4 o = { (bf16_t)a.x, (bf16_t)a.y, (bf16_t)a.z, (bf16_t)a.w };
    *(bf16x4*)(h + i4) = o;
}

// ---------------- launcher ----------------

extern "C" void kernel_launch(void* const* d_in, const int* in_sizes, int n_in,
                              void* d_out, int out_size, void* d_ws, size_t ws_size,
                              hipStream_t stream) {
    const float* X  = (const float*)d_in[0];
    // d_in[1] = batch_indices: group->MLP->ungroup is an identity permutation; unused.
    const float* W1 = (const float*)d_in[2];
    const float* b1 = (const float*)d_in[3];
    const float* W2 = (const float*)d_in[4];
    const float* b2 = (const float*)d_in[5];
    const float* Wc = (const float*)d_in[6];
    const float* bc = (const float*)d_in[7];
    float* out = (float*)d_out;

    const int M    = in_sizes[1];            // 2048
    const int FEAT = in_sizes[0] / M;        // 12544
    const int HID  = in_sizes[3];            // 1024
    const int NC   = in_sizes[7];            // 81
    const int NCP  = 128;                    // padded class dim for MFMA

    char* ws = (char*)d_ws;
    size_t off = 0;
    auto alloc = [&](size_t bytes) {
        char* p = ws + off;
        off += (bytes + 255) & ~(size_t)255;
        return p;
    };
    bf16_t* W1T = (bf16_t*)alloc((size_t)FEAT * HID * 2);
    bf16_t* W2T = (bf16_t*)alloc((size_t)HID * HID * 2);
    bf16_t* WcT = (bf16_t*)alloc((size_t)NCP * HID * 2);
    bf16_t* h1  = (bf16_t*)alloc((size_t)M * HID * 2);
    bf16_t* h2  = (bf16_t*)alloc((size_t)M * HID * 2);
    float*  P   = (float*)(ws + off);

    size_t rem  = ws_size > off ? ws_size - off : 0;
    size_t perS = (size_t)M * HID * 4;
    // FEAT=12544 divides exactly by {1,2,4,8}; FEAT/S stays %32==0.
    int S1 = (rem >= 8 * perS) ? 8 : (rem >= 4 * perS) ? 4 : (rem >= 2 * perS) ? 2 : 1;
    int KC1 = FEAT / S1;

    // 1) prep: W1/W2/Wc -> transposed bf16 [N][K]
    int t1 = (HID / 32) * (FEAT / 32);
    int t2 = (HID / 32) * (HID / 32);
    int t3 = (NCP / 32) * (HID / 32);
    prep_weights<<<t1 + t2 + t3, 256, 0, stream>>>(
        W1, W1T, W2, W2T, Wc, WcT, FEAT, HID, NC, NCP, t1, t2);

    // 2) layer 1: h1 = relu(X@W1 + b1); X read as fp32, cvt at fragment time
    gemm128_xf32<<<dim3(M / 128, HID / 128, S1), 256, 0, stream>>>(X, W1T, P, M, HID, FEAT, KC1);
    switch (S1) {
        case 8: reduce_relu_bf16_k<8><<<(M * HID / 4 + 255) / 256, 256, 0, stream>>>(P, b1, h1, M * HID, HID - 1); break;
        case 4: reduce_relu_bf16_k<4><<<(M * HID / 4 + 255) / 256, 256, 0, stream>>>(P, b1, h1, M * HID, HID - 1); break;
        case 2: reduce_relu_bf16_k<2><<<(M * HID / 4 + 255) / 256, 256, 0, stream>>>(P, b1, h1, M * HID, HID - 1); break;
        default: reduce_relu_bf16_k<1><<<(M * HID / 4 + 255) / 256, 256, 0, stream>>>(P, b1, h1, M * HID, HID - 1); break;
    }

    // 3) layer 2: h2 = relu(h1@W2 + b2) — fused epilogue
    gemm64_fused<true, bf16_t><<<dim3(M / 64, HID / 64), 256, 0, stream>>>(h1, W2T, b2, h2, HID, HID);

    // 4) classifier: out = h2@Wc + bc — fused epilogue, fp32 out (n<81)
    gemm64_fused<false, float><<<dim3(M / 64, NCP / 64), 256, 0, stream>>>(h2, WcT, bc, out, HID, NC);
}

// Round 7
// 311.402 us; speedup vs baseline: 1.1719x; 1.1719x over previous
//
#include <hip/hip_runtime.h>
#include <hip/hip_bf16.h>
#include <stdint.h>

typedef __bf16 bf16_t;
typedef __bf16 bf16x2 __attribute__((ext_vector_type(2)));
typedef __bf16 bf16x4 __attribute__((ext_vector_type(4)));
typedef __bf16 bf16x8 __attribute__((ext_vector_type(8)));
typedef float f32x4 __attribute__((ext_vector_type(4)));

// Async global->LDS, 16B per lane. LDS dst is wave-uniform base + lane*16.
__device__ __forceinline__ void async_ld16(const bf16_t* g, bf16_t* lds) {
    __builtin_amdgcn_global_load_lds(
        (__attribute__((address_space(1))) void*)g,
        (__attribute__((address_space(3))) void*)lds,
        16, 0, 0);
}

// ---------------- fused prep: X convert + 3 weight transposes ----------------

__device__ __forceinline__ void transpose_tile(
    const float* __restrict__ in, bf16_t* __restrict__ out,
    int R, int C, int Cp, int tileIdx, int tid, float (*tile)[33])
{
    const int tilesX = Cp / 32;
    const int c0 = (tileIdx % tilesX) * 32;
    const int r0 = (tileIdx / tilesX) * 32;
    const int tx = tid & 31;
    const int ty = tid >> 5;   // 0..7
#pragma unroll
    for (int i = 0; i < 32; i += 8) {
        int rr = r0 + ty + i, cc = c0 + tx;
        float v = 0.f;
        if (cc < C) v = in[(size_t)rr * C + cc];   // R tiles always in-bounds
        tile[ty + i][tx] = v;
    }
    __syncthreads();
    // vectorized write-back: each thread stores bf16x2 (two consecutive R cols)
    const int px = tid & 15;
    const int py = tid >> 4;   // 0..15
#pragma unroll
    for (int i = 0; i < 32; i += 16) {
        int oc = c0 + py + i;         // output row (original column, zero-padded)
        int orr = r0 + px * 2;        // output col (original row), pair base
        bf16x2 o = { (bf16_t)tile[px * 2][py + i], (bf16_t)tile[px * 2 + 1][py + i] };
        *(bf16x2*)&out[(size_t)oc * R + orr] = o;
    }
}

__global__ void prep_all(const float* __restrict__ X, bf16_t* __restrict__ Xb, int n4,
                         const float* __restrict__ W1, bf16_t* __restrict__ W1T,
                         const float* __restrict__ W2, bf16_t* __restrict__ W2T,
                         const float* __restrict__ Wc, bf16_t* __restrict__ WcT,
                         int FEAT, int HID, int NC, int NCP,
                         int nCvt, int t1, int t2)
{
    __shared__ float tile[32][33];
    int bid = blockIdx.x;
    int tid = threadIdx.x;
    if (bid < nCvt) {
        int i = bid * 256 + tid;
        if (i < n4) {
            float4 v = ((const float4*)X)[i];
            bf16x4 o = { (bf16_t)v.x, (bf16_t)v.y, (bf16_t)v.z, (bf16_t)v.w };
            ((bf16x4*)Xb)[i] = o;
        }
        return;
    }
    bid -= nCvt;
    if (bid < t1) { transpose_tile(W1, W1T, FEAT, HID, HID, bid, tid, tile); return; }
    bid -= t1;
    if (bid < t2) { transpose_tile(W2, W2T, HID, HID, HID, bid, tid, tile); return; }
    bid -= t2;
    transpose_tile(Wc, WcT, HID, NC, NCP, bid, tid, tile);
}

// ---------------- GEMM 128x128, BK=64 + XOR swizzle, split-K -----------------
// A: [M][K] bf16. B: [N][K] bf16 (weights transposed). P: [S][M][N] fp32.
// BK=64 rows are 128 B (8 x 16B chunks) = exact bank wrap -> XOR swizzle:
// physical chunk = logical chunk ^ (row & 7). This is the gemm64_fused pattern,
// measured 0 conflicts in R4 (R3's BK=64 regression had NO swizzle -> 19M).
// Staging fetches the permuted global chunk so LDS writes stay lane-contiguous.
// Chunk s covers K range [s*KC, min((s+1)*KC, K)); all chunks %64.
__global__ __launch_bounds__(256) void gemm128_bk64(
    const bf16_t* __restrict__ A, const bf16_t* __restrict__ B,
    float* __restrict__ P, int M, int N, int K, int KC)
{
    __shared__ __align__(16) bf16_t Asm[128 * 64];
    __shared__ __align__(16) bf16_t Bsm[128 * 64];

    const int tid  = threadIdx.x;
    const int wave = tid >> 6;
    const int lane = tid & 63;
    const int bm = blockIdx.x, bn = blockIdx.y, s = blockIdx.z;

    const int Koff = s * KC;
    const int Kc   = (K - Koff < KC) ? (K - Koff) : KC;   // multiple of 64

    const bf16_t* Ab = A + (size_t)bm * 128 * K + Koff;
    const bf16_t* Bb = B + (size_t)bn * 128 * K + Koff;

    // staging: 64 lanes x 16B = 8 rows of 128 B per issue. row-in-group =
    // lane>>3, landing chunk = lane&7; fetch logical chunk (lane&7)^(row&7).
    const int sr = lane >> 3;
    const int sk = ((lane & 7) ^ (sr & 7)) * 8;

    // wave quadrant (64x64) within 128x128 tile
    const int wm = (wave >> 1) * 64;
    const int wn = (wave & 1) * 64;
    const int r  = lane & 15;
    const int q  = lane >> 4;

    f32x4 acc[4][4];
#pragma unroll
    for (int i = 0; i < 4; ++i)
#pragma unroll
        for (int j = 0; j < 4; ++j)
            acc[i][j] = f32x4{0.f, 0.f, 0.f, 0.f};

    for (int k0 = 0; k0 < Kc; k0 += 64) {
        __syncthreads();
        // A: 16 issues of 8 rows (4 per wave); B: same
#pragma unroll
        for (int i = 0; i < 4; ++i) {
            const int rb = wave * 32 + i * 8;
            async_ld16(Ab + (size_t)(rb + sr) * K + (k0 + sk), &Asm[rb * 64]);
            async_ld16(Bb + (size_t)(rb + sr) * K + (k0 + sk), &Bsm[rb * 64]);
        }
        __syncthreads();

        // two k-halves; per-half frag chunk = (rnd*4+q)^(r&7)  [0 conflicts, R4]
#pragma unroll
        for (int rnd = 0; rnd < 2; ++rnd) {
            bf16x8 af[4], bfr[4];
#pragma unroll
            for (int i = 0; i < 4; ++i)
                af[i] = *(const bf16x8*)&Asm[(wm + i * 16 + r) * 64
                                             + ((rnd * 4 + q) ^ (r & 7)) * 8];
#pragma unroll
            for (int j = 0; j < 4; ++j)
                bfr[j] = *(const bf16x8*)&Bsm[(wn + j * 16 + r) * 64
                                              + ((rnd * 4 + q) ^ (r & 7)) * 8];
#pragma unroll
            for (int i = 0; i < 4; ++i)
#pragma unroll
                for (int j = 0; j < 4; ++j)
                    acc[i][j] = __builtin_amdgcn_mfma_f32_16x16x32_bf16(af[i], bfr[j], acc[i][j], 0, 0, 0);
        }
    }

    // epilogue: C/D layout col=lane&15, row=(lane>>4)*4+reg
    float* Pb = P + ((size_t)s * M + (size_t)bm * 128) * N + (size_t)bn * 128;
    const int r4 = q * 4;
#pragma unroll
    for (int i = 0; i < 4; ++i)
#pragma unroll
        for (int j = 0; j < 4; ++j)
#pragma unroll
            for (int rg = 0; rg < 4; ++rg)
                Pb[(size_t)(wm + i * 16 + r4 + rg) * N + (wn + j * 16 + r)] = acc[i][j][rg];
}

// ---------------- GEMM 64x64, BK=64, full-K, fused bias(+ReLU) epilogue ------
// Unchanged from R4 (0 conflicts measured).
template <bool RELU, typename OutT>
__global__ __launch_bounds__(256) void gemm64_fused(
    const bf16_t* __restrict__ A, const bf16_t* __restrict__ B,
    const float* __restrict__ bias, OutT* __restrict__ out,
    int K, int Nout)
{
    __shared__ __align__(16) bf16_t Asm[64 * 64];
    __shared__ __align__(16) bf16_t Bsm[64 * 64];

    const int tid  = threadIdx.x;
    const int wave = tid >> 6;
    const int lane = tid & 63;
    const int bm = blockIdx.x, bn = blockIdx.y;

    const bf16_t* Ab = A + (size_t)bm * 64 * K;
    const bf16_t* Bb = B + (size_t)bn * 64 * K;

    const int sr = lane >> 3;
    const int sk = ((lane & 7) ^ (sr & 7)) * 8;

    const int wm = (wave >> 1) * 32;
    const int wn = (wave & 1) * 32;
    const int r  = lane & 15;
    const int q  = lane >> 4;

    f32x4 acc[2][2];
#pragma unroll
    for (int i = 0; i < 2; ++i)
#pragma unroll
        for (int j = 0; j < 2; ++j)
            acc[i][j] = f32x4{0.f, 0.f, 0.f, 0.f};

    for (int k0 = 0; k0 < K; k0 += 64) {
        __syncthreads();
#pragma unroll
        for (int i = 0; i < 2; ++i) {
            const int rb = wave * 16 + i * 8;
            async_ld16(Ab + (size_t)(rb + sr) * K + (k0 + sk), &Asm[rb * 64]);
            async_ld16(Bb + (size_t)(rb + sr) * K + (k0 + sk), &Bsm[rb * 64]);
        }
        __syncthreads();

#pragma unroll
        for (int rnd = 0; rnd < 2; ++rnd) {
            bf16x8 af[2], bfr[2];
#pragma unroll
            for (int i = 0; i < 2; ++i)
                af[i] = *(const bf16x8*)&Asm[(wm + i * 16 + r) * 64
                                             + ((rnd * 4 + q) ^ (r & 7)) * 8];
#pragma unroll
            for (int j = 0; j < 2; ++j)
                bfr[j] = *(const bf16x8*)&Bsm[(wn + j * 16 + r) * 64
                                              + ((rnd * 4 + q) ^ (r & 7)) * 8];
#pragma unroll
            for (int i = 0; i < 2; ++i)
#pragma unroll
                for (int j = 0; j < 2; ++j)
                    acc[i][j] = __builtin_amdgcn_mfma_f32_16x16x32_bf16(af[i], bfr[j], acc[i][j], 0, 0, 0);
        }
    }

    const int r4 = (lane >> 4) * 4;
    const int c  = lane & 15;
#pragma unroll
    for (int i = 0; i < 2; ++i)
#pragma unroll
        for (int j = 0; j < 2; ++j) {
            const int col = bn * 64 + wn + j * 16 + c;
            if (col < Nout) {
                const float bv = bias[col];
#pragma unroll
                for (int rg = 0; rg < 4; ++rg) {
                    const int row = bm * 64 + wm + i * 16 + r4 + rg;
                    float v = acc[i][j][rg] + bv;
                    if (RELU) v = fmaxf(v, 0.f);
                    out[(size_t)row * Nout + col] = (OutT)v;
                }
            }
        }
}

// ---------------- split-K reduction for layer 1 ----------------

template <int S>
__global__ void reduce_relu_bf16_k(const float* __restrict__ P, const float* __restrict__ bias,
                                   bf16_t* __restrict__ h, int MN, int Nm1) {
    int i4 = (blockIdx.x * 256 + threadIdx.x) * 4;
    if (i4 >= MN) return;
    int n = i4 & Nm1;
    float4 a = *(const float4*)(bias + n);
#pragma unroll
    for (int s = 0; s < S; ++s) {
        float4 p = *(const float4*)(P + (size_t)s * MN + i4);
        a.x += p.x; a.y += p.y; a.z += p.z; a.w += p.w;
    }
    a.x = fmaxf(a.x, 0.f); a.y = fmaxf(a.y, 0.f);
    a.z = fmaxf(a.z, 0.f); a.w = fmaxf(a.w, 0.f);
    bf16x4 o = { (bf16_t)a.x, (bf16_t)a.y, (bf16_t)a.z, (bf16_t)a.w };
    *(bf16x4*)(h + i4) = o;
}

// ---------------- launcher ----------------

extern "C" void kernel_launch(void* const* d_in, const int* in_sizes, int n_in,
                              void* d_out, int out_size, void* d_ws, size_t ws_size,
                              hipStream_t stream) {
    const float* X  = (const float*)d_in[0];
    // d_in[1] = batch_indices: group->MLP->ungroup is an identity permutation; unused.
    const float* W1 = (const float*)d_in[2];
    const float* b1 = (const float*)d_in[3];
    const float* W2 = (const float*)d_in[4];
    const float* b2 = (const float*)d_in[5];
    const float* Wc = (const float*)d_in[6];
    const float* bc = (const float*)d_in[7];
    float* out = (float*)d_out;

    const int M    = in_sizes[1];            // 2048
    const int FEAT = in_sizes[0] / M;        // 12544
    const int HID  = in_sizes[3];            // 1024
    const int NC   = in_sizes[7];            // 81
    const int NCP  = 128;                    // padded class dim for MFMA

    char* ws = (char*)d_ws;
    size_t off = 0;
    auto alloc = [&](size_t bytes) {
        char* p = ws + off;
        off += (bytes + 255) & ~(size_t)255;
        return p;
    };
    bf16_t* Xb  = (bf16_t*)alloc((size_t)M * FEAT * 2);
    bf16_t* W1T = (bf16_t*)alloc((size_t)FEAT * HID * 2);
    bf16_t* W2T = (bf16_t*)alloc((size_t)HID * HID * 2);
    bf16_t* WcT = (bf16_t*)alloc((size_t)NCP * HID * 2);
    bf16_t* h1  = (bf16_t*)alloc((size_t)M * HID * 2);
    bf16_t* h2  = (bf16_t*)alloc((size_t)M * HID * 2);
    float*  P   = (float*)(ws + off);

    size_t rem  = ws_size > off ? ws_size - off : 0;
    size_t perS = (size_t)M * HID * 4;
    int S1 = (rem >= 8 * perS) ? 8 : (rem >= 4 * perS) ? 4 : (rem >= 2 * perS) ? 2 : 1;
    // chunk size: ceil(FEAT/S1) rounded up to multiple of 64 (BK). FEAT=12544,
    // S1=8 -> KC1=1600: 7 chunks of 1600 + last 1344, both %64.
    int KC1 = ((FEAT / S1 + 63) / 64) * 64;

    // 1) fused prep: X->bf16, W1/W2/Wc -> transposed bf16 [N][K]
    int n4   = (M * FEAT) / 4;
    int nCvt = (n4 + 255) / 256;
    int t1 = (HID / 32) * (FEAT / 32);
    int t2 = (HID / 32) * (HID / 32);
    int t3 = (NCP / 32) * (HID / 32);
    prep_all<<<nCvt + t1 + t2 + t3, 256, 0, stream>>>(
        X, Xb, n4, W1, W1T, W2, W2T, Wc, WcT, FEAT, HID, NC, NCP, nCvt, t1, t2);

    // 2) layer 1: h1 = relu(X@W1 + b1), split-K, BK=64 swizzled
    gemm128_bk64<<<dim3(M / 128, HID / 128, S1), 256, 0, stream>>>(Xb, W1T, P, M, HID, FEAT, KC1);
    switch (S1) {
        case 8: reduce_relu_bf16_k<8><<<(M * HID / 4 + 255) / 256, 256, 0, stream>>>(P, b1, h1, M * HID, HID - 1); break;
        case 4: reduce_relu_bf16_k<4><<<(M * HID / 4 + 255) / 256, 256, 0, stream>>>(P, b1, h1, M * HID, HID - 1); break;
        case 2: reduce_relu_bf16_k<2><<<(M * HID / 4 + 255) / 256, 256, 0, stream>>>(P, b1, h1, M * HID, HID - 1); break;
        default: reduce_relu_bf16_k<1><<<(M * HID / 4 + 255) / 256, 256, 0, stream>>>(P, b1, h1, M * HID, HID - 1); break;
    }

    // 3) layer 2: h2 = relu(h1@W2 + b2) — fused epilogue
    gemm64_fused<true, bf16_t><<<dim3(M / 64, HID / 64), 256, 0, stream>>>(h1, W2T, b2, h2, HID, HID);

    // 4) classifier: out = h2@Wc + bc — fused epilogue, fp32 out (n<81)
    gemm64_fused<false, float><<<dim3(M / 64, NCP / 64), 256, 0, stream>>>(h2, WcT, bc, out, HID, NC);
}